// Round 15
// baseline (161.890 us; speedup 1.0000x reference)
//
#include <hip/hip_runtime.h>
#include <math.h>

// Problem constants (fixed by setup_inputs)
#define BB 256      // batch
#define TT 256      // time steps
#define NQ 1000     // num_q
#define DK 128
#define DV 128
#define CC 32

typedef short s16x8 __attribute__((ext_vector_type(8)));   // 8 bf16 bit-patterns
typedef float f32x4 __attribute__((ext_vector_type(4)));
typedef float f32x2 __attribute__((ext_vector_type(2)));

__device__ __forceinline__ float fast_sigmoid(float x) {
    x = fminf(fmaxf(x, -30.f), 30.f);
    return 1.f / (1.f + __expf(-x));
}
__device__ __forceinline__ float fast_tanh(float x) {
    x = fminf(fmaxf(x, -15.f), 15.f);
    float t = __expf(2.f * x);
    return (t - 1.f) / (t + 1.f);
}
__device__ __forceinline__ unsigned short f2bf(float f) {   // RNE fp32->bf16
    unsigned u = __float_as_uint(f);
    u += 0x7fffu + ((u >> 16) & 1u);
    return (unsigned short)(u >> 16);
}
__device__ __forceinline__ float bf2f(unsigned short h) {
    return __uint_as_float((unsigned)h << 16);
}
__device__ __forceinline__ f32x2 mk2(float x, float y) { f32x2 r; r.x = x; r.y = y; return r; }
__device__ __forceinline__ f32x2 fma2(f32x2 a, f32x2 b, f32x2 c) {
    return __builtin_elementwise_fma(a, b, c);
}
__device__ __forceinline__ s16x8 cvt8(float4 v0, float4 v1) {
    s16x8 f;
    f[0] = (short)f2bf(v0.x); f[1] = (short)f2bf(v0.y);
    f[2] = (short)f2bf(v0.z); f[3] = (short)f2bf(v0.w);
    f[4] = (short)f2bf(v1.x); f[5] = (short)f2bf(v1.y);
    f[6] = (short)f2bf(v1.z); f[7] = (short)f2bf(v1.w);
    return f;
}

// ---------------------------------------------------------------------------
// conv_kernel: build bf16 TRANSPOSED weights in ws (B-operand layout Wt[n][k])
// ---------------------------------------------------------------------------
__global__ __launch_bounds__(256) void conv_kernel(
    const float* __restrict__ eW, const float* __restrict__ aW,
    const float* __restrict__ fW, const float* __restrict__ Mk,
    unsigned short* __restrict__ eWt, unsigned short* __restrict__ aWt,
    unsigned short* __restrict__ fWat, unsigned short* __restrict__ fWbt,
    unsigned short* __restrict__ Mkt)
{
    int idx = blockIdx.x * 256 + threadIdx.x;
    if (idx < 16384) {
        int n = idx >> 7, k = idx & 127;
        eWt[idx] = f2bf(eW[k * 128 + n]);
    } else if (idx < 32768) {
        int i = idx - 16384; int n = i >> 7, k = i & 127;
        aWt[i] = f2bf(aW[k * 128 + n]);
    } else if (idx < 49152) {
        int i = idx - 32768; int n = i >> 7, k = i & 127;
        fWat[i] = f2bf(fW[k * 128 + n]);
    } else if (idx < 65536) {
        int i = idx - 49152; int n = i >> 7, k = i & 127;
        fWbt[i] = f2bf(fW[(128 + k) * 128 + n]);
    } else if (idx < 69632) {
        int i = idx - 65536; int n = i >> 7, k = i & 127;   // n=c 0..31
        Mkt[i] = f2bf(Mk[k * 32 + n]);
    }
}

// ---------------------------------------------------------------------------
// pre_kernel v2 (measured best form).
// ---------------------------------------------------------------------------
__global__ __launch_bounds__(256) void pre_kernel(
    const int* __restrict__ skills, const int* __restrict__ responses,
    const float* __restrict__ k_emb, const float* __restrict__ v_emb,
    const float* __restrict__ fb, const float* __restrict__ eb,
    const float* __restrict__ ab,
    const unsigned short* __restrict__ Mkt, const unsigned short* __restrict__ fWbt,
    const unsigned short* __restrict__ eWt, const unsigned short* __restrict__ aWt,
    float* __restrict__ Wo, unsigned* __restrict__ EA,
    unsigned short* __restrict__ Ko, float* __restrict__ outTrue,
    int t0, int Tc)
{
    const int tid = threadIdx.x;
    const int lane = tid & 63;
    const int m_base = (tid >> 6) * 16;
    const int mrow = lane & 15, quad = lane >> 4;
    const size_t base = (size_t)blockIdx.x * 64;

    __shared__ __align__(16) unsigned short Wlds[128 * 136];   // 34.8 KB

    // per-lane gather row (A-side): row = base + m_base + mrow
    int grow = (int)base + m_base + mrow;
    int gb = grow / Tc;
    int gt = t0 + (grow - gb * Tc);
    int gi = gb * TT + gt;
    int s = skills[gi];
    int r = responses[gi];
    int q = s + NQ * ((r > -1) ? r : 0);
    if (quad == 0 && gt >= 1) outTrue[gb * (TT - 1) + (gt - 1)] = (float)r;

    // stage Mkt rows 0..31
    {
        int n = tid >> 3, k0 = (tid & 7) * 16;
        *(s16x8*)&Wlds[n * 136 + k0]     = *(const s16x8*)&Mkt[n * 128 + k0];
        *(s16x8*)&Wlds[n * 136 + k0 + 8] = *(const s16x8*)&Mkt[n * 128 + k0 + 8];
    }

    // gather kt A-frags direct to regs: aF[kb] = kt[row][kb*32 + quad*8 ..+7]
    s16x8 aF[4];
    {
        const float* kr = k_emb + (size_t)s * DK + quad * 8;
#pragma unroll
        for (int kb = 0; kb < 4; ++kb)
            aF[kb] = cvt8(*(const float4*)(kr + kb * 32),
                          *(const float4*)(kr + kb * 32 + 4));
    }
    __syncthreads();   // [1] Mkt staged

    // logits (NT=2) + in-register softmax -> Wo
    {
        f32x4 l0 = {0.f, 0.f, 0.f, 0.f}, l1 = {0.f, 0.f, 0.f, 0.f};
#pragma unroll
        for (int kb = 0; kb < 4; ++kb) {
            s16x8 b0 = *(const s16x8*)&Wlds[mrow * 136 + kb * 32 + quad * 8];
            s16x8 b1 = *(const s16x8*)&Wlds[(16 + mrow) * 136 + kb * 32 + quad * 8];
            l0 = __builtin_amdgcn_mfma_f32_16x16x32_bf16(aF[kb], b0, l0, 0, 0, 0);
            l1 = __builtin_amdgcn_mfma_f32_16x16x32_bf16(aF[kb], b1, l1, 0, 0, 0);
        }
        // lane holds cols {mrow, 16+mrow} for rows m_base + quad*4 + reg
#pragma unroll
        for (int reg = 0; reg < 4; ++reg) {
            float a0 = l0[reg], a1 = l1[reg];
            float m = fmaxf(a0, a1);
#pragma unroll
            for (int off = 1; off < 16; off <<= 1)
                m = fmaxf(m, __shfl_xor(m, off, 64));
            float e0 = __expf(a0 - m), e1 = __expf(a1 - m);
            float ssum = e0 + e1;
#pragma unroll
            for (int off = 1; off < 16; off <<= 1)
                ssum += __shfl_xor(ssum, off, 64);
            float inv = 1.f / ssum;
            size_t rowg = base + m_base + quad * 4 + reg;
            Wo[rowg * 32 + mrow]      = e0 * inv;
            Wo[rowg * 32 + 16 + mrow] = e1 * inv;
        }
    }
    __syncthreads();   // [2] logits' Wlds reads done

    // stage fWbt
    {
        int n = tid >> 1, k0 = (tid & 1) * 64;
#pragma unroll
        for (int j = 0; j < 8; ++j)
            *(s16x8*)&Wlds[n * 136 + k0 + j * 8] = *(const s16x8*)&fWbt[n * 128 + k0 + j * 8];
    }
    __syncthreads();   // [3]

    // gather vt frags early (global latency overlaps ck MFMA below)
    s16x8 vF[4];
    {
        const float* vr = v_emb + (size_t)q * DV + quad * 8;
#pragma unroll
        for (int kb = 0; kb < 4; ++kb)
            vF[kb] = cvt8(*(const float4*)(vr + kb * 32),
                          *(const float4*)(vr + kb * 32 + 4));
    }

    // ck = kt@fWb + fb -> Ko
#pragma unroll
    for (int nt = 0; nt < 8; ++nt) {
        f32x4 acc = {0.f, 0.f, 0.f, 0.f};
#pragma unroll
        for (int kb = 0; kb < 4; ++kb) {
            s16x8 bf = *(const s16x8*)&Wlds[(nt * 16 + mrow) * 136 + kb * 32 + quad * 8];
            acc = __builtin_amdgcn_mfma_f32_16x16x32_bf16(aF[kb], bf, acc, 0, 0, 0);
        }
        int col = nt * 16 + mrow;
        float fbv = fb[col];
#pragma unroll
        for (int reg = 0; reg < 4; ++reg) {
            size_t rr = base + m_base + quad * 4 + reg;
            Ko[rr * 128 + col] = f2bf(acc[reg] + fbv);
        }
    }
    __syncthreads();   // [4] ck's Wlds reads done

    // stage eWt
    {
        int n = tid >> 1, k0 = (tid & 1) * 64;
#pragma unroll
        for (int j = 0; j < 8; ++j)
            *(s16x8*)&Wlds[n * 136 + k0 + j * 8] = *(const s16x8*)&eWt[n * 128 + k0 + j * 8];
    }
    __syncthreads();   // [5]

    // et = sigmoid(vt@eW + eb) -> registers
    float etr[8][4];
#pragma unroll
    for (int nt = 0; nt < 8; ++nt) {
        f32x4 acc = {0.f, 0.f, 0.f, 0.f};
#pragma unroll
        for (int kb = 0; kb < 4; ++kb) {
            s16x8 bf = *(const s16x8*)&Wlds[(nt * 16 + mrow) * 136 + kb * 32 + quad * 8];
            acc = __builtin_amdgcn_mfma_f32_16x16x32_bf16(vF[kb], bf, acc, 0, 0, 0);
        }
        int col = nt * 16 + mrow;
        float ebv = eb[col];
#pragma unroll
        for (int reg = 0; reg < 4; ++reg)
            etr[nt][reg] = fast_sigmoid(acc[reg] + ebv);
    }
    __syncthreads();   // [6] et's Wlds reads done

    // stage aWt
    {
        int n = tid >> 1, k0 = (tid & 1) * 64;
#pragma unroll
        for (int j = 0; j < 8; ++j)
            *(s16x8*)&Wlds[n * 136 + k0 + j * 8] = *(const s16x8*)&aWt[n * 128 + k0 + j * 8];
    }
    __syncthreads();   // [7]

    // at = tanh(vt@aW + ab); pack (et,at) -> EA
#pragma unroll
    for (int nt = 0; nt < 8; ++nt) {
        f32x4 acc = {0.f, 0.f, 0.f, 0.f};
#pragma unroll
        for (int kb = 0; kb < 4; ++kb) {
            s16x8 bf = *(const s16x8*)&Wlds[(nt * 16 + mrow) * 136 + kb * 32 + quad * 8];
            acc = __builtin_amdgcn_mfma_f32_16x16x32_bf16(vF[kb], bf, acc, 0, 0, 0);
        }
        int col = nt * 16 + mrow;
        float abv = ab[col];
#pragma unroll
        for (int reg = 0; reg < 4; ++reg) {
            size_t rr = base + m_base + quad * 4 + reg;
            int bb = (int)(rr / (size_t)Tc);
            int t  = (int)(rr - (size_t)bb * Tc);
            size_t o4 = (((size_t)bb * (Tc >> 5) + (t >> 5)) * 8 + ((t >> 2) & 7)) * 128 + col;
            unsigned lo = f2bf(etr[nt][reg]);
            unsigned hi = (unsigned)f2bf(fast_tanh(acc[reg] + abv)) << 16;
            EA[o4 * 4 + (t & 3)] = hi | lo;
        }
    }
}

// ---------------------------------------------------------------------------
// fused_kernel v18 (seq + post) — R25: R13 structure, ONE change: ALL
//  sched_barrier(0) fences REMOVED from the producer chunk.
//  Theory: SB(0) order-pinning defeats the compiler's counted-lgkmcnt
//  placement (guide m141: 874->510 TF from exactly this; Common-mistake #5).
//  With SB pinning PREF-then-STEP, the compiler plausibly emits a full
//  lgkmcnt(0) drain before each STEP — waiting on the just-issued NEXT-step
//  prefetch — exposing a full LDS round-trip every step. This fits all 7
//  nulls: the drain is insensitive to prefetch distance (R7), TLP (R9),
//  memory residency (R10/R13), priority (R12), and I$ (R14). Every fused
//  variant ever benched inherited these fences; never A/B'd. Unrolled loop
//  kept (R13 best); compiler now free to hoist ds_reads and use counted
//  waits.
// ---------------------------------------------------------------------------

#define CH 32
#define WROW 36     // Wl row stride (floats)
#define RSTR 136    // fWl row stride (shorts)
#define PSTR 132    // rt partial row stride (floats)

#define LOAD_W(gg) do {                                                       \
    const float* ws = Wb + (size_t)(gg) * CH * 32;                            \
    wr0 = *(const float4*)(ws + dd * 8);                                      \
    wr1 = *(const float4*)(ws + dd * 8 + 4);                                  \
} while (0)

#define PUB_W(gg) do {                                                        \
    float* wd = &Wl[(gg) & 1][lr * WROW + lq * 8];                            \
    *(float4*)wd = wr0; *(float4*)(wd + 4) = wr1;                             \
} while (0)

// stager: copy chunk gg's EA block global->LDS, transposed to [tl][dd]
#define STAGE_EA(gg) do {                                                     \
    const uint4* src = EA4 + ((size_t)(bq + (gg))) * 1024 + dd;               \
    unsigned* dst = &EAl[(gg) & 1][0];                                        \
    _Pragma("unroll")                                                         \
    for (int j = 0; j < 8; ++j) {                                             \
        uint4 v = src[j * 128];                                               \
        dst[(4 * j + 0) * 128 + dd] = v.x;                                    \
        dst[(4 * j + 1) * 128 + dd] = v.y;                                    \
        dst[(4 * j + 2) * 128 + dd] = v.z;                                    \
        dst[(4 * j + 3) * 128 + dd] = v.w;                                    \
    }                                                                         \
} while (0)

// prefetch this producer's 16 w floats of row `rowidx` into 4 named float4s
#define PREF4(A0,A1,A2,A3, rowidx) do {                                       \
    const float* _wr = wlc + (rowidx) * WROW;                                 \
    A0 = *(const float4*)(_wr + 0);  A1 = *(const float4*)(_wr + 4);          \
    A2 = *(const float4*)(_wr + 8);  A3 = *(const float4*)(_wr + 12);         \
} while (0)

// one chain step on this producer's 16-c half; f32 partial -> own LDS array
#define STEP4(A0,A1,A2,A3, EAV, tl) do {                                      \
    f32x2 w2[8];                                                              \
    w2[0] = mk2(A0.x, A0.y); w2[1] = mk2(A0.z, A0.w);                         \
    w2[2] = mk2(A1.x, A1.y); w2[3] = mk2(A1.z, A1.w);                         \
    w2[4] = mk2(A2.x, A2.y); w2[5] = mk2(A2.z, A2.w);                         \
    w2[6] = mk2(A3.x, A3.y); w2[7] = mk2(A3.z, A3.w);                         \
    unsigned ea = (EAV);                                                      \
    float e  = __uint_as_float(ea << 16);                                     \
    float av = __uint_as_float(ea & 0xffff0000u);                             \
    f32x2 ne2 = mk2(-e, -e);                                                  \
    f32x2 a2  = mk2(av, av);                                                  \
    f32x2 r0 = mk2(0.f, 0.f), r1 = r0, r2 = r0, r3 = r0;                      \
    r0 = fma2(w2[0], Mv2[0], r0); r1 = fma2(w2[1], Mv2[1], r1);               \
    r2 = fma2(w2[2], Mv2[2], r2); r3 = fma2(w2[3], Mv2[3], r3);               \
    r0 = fma2(w2[4], Mv2[4], r0); r1 = fma2(w2[5], Mv2[5], r1);               \
    r2 = fma2(w2[6], Mv2[6], r2); r3 = fma2(w2[7], Mv2[7], r3);               \
    f32x2 rs = (r0 + r1) + (r2 + r3);                                         \
    slp[(tl) * PSTR + dd] = rs.x + rs.y;                                      \
    _Pragma("unroll")                                                         \
    for (int i = 0; i < 8; ++i)                                               \
        Mv2[i] = fma2(w2[i], fma2(ne2, Mv2[i], a2), Mv2[i]);                  \
} while (0)

// chunk: distance-1 pipeline for w (LDS) and ea (LDS); NO sched_barriers —
// compiler free to hoist loads and place counted lgkmcnt waits.
#define SEQ_CHUNK4(gg) do {                                                   \
    const float* wlc = Wl[(gg) & 1] + ch16;                                   \
    const unsigned* eac = &EAl[(gg) & 1][0];                                  \
    float* slp = ch ? &rt1[(gg) & 1][0] : &rt0[(gg) & 1][0];                  \
    PREF4(w0, w1, w2_, w3_, 0);                                               \
    unsigned eaw = eac[dd], eau;                                              \
    _Pragma("unroll")                                                         \
    for (int tp = 0; tp < 16; ++tp) {                                         \
        PREF4(u0, u1, u2, u3, 2 * tp + 1);                                    \
        eau = eac[(2 * tp + 1) * 128 + dd];                                   \
        STEP4(w0, w1, w2_, w3_, eaw, 2 * tp);                                 \
        PREF4(w0, w1, w2_, w3_,                                               \
              (2 * tp + 2 < 32) ? (2 * tp + 2) : 31);                         \
        eaw = eac[((2 * tp + 2 < 32) ? (2 * tp + 2) : 31) * 128 + dd];        \
        STEP4(u0, u1, u2, u3, eau, 2 * tp + 1);                               \
    }                                                                         \
} while (0)

__device__ __forceinline__ void consume_chunk(
    int gc, const float* r0p, const float* r1p, const unsigned short* fWl,
    int b, int Tc, int t0,
    const unsigned short* __restrict__ Ko, const float* __restrict__ pW,
    float pbv, float* __restrict__ pred, int tid)
{
    const int lane = tid & 63;
    const int cw = (tid >> 6) & 1;          // consumer wave 0/1 -> rows cw*16..+15
    const int mrow = lane & 15, quad = lane >> 4;
    size_t rbase = (size_t)b * Tc + gc * CH + cw * 16 + quad * 4;

    // prefetch ALL Ko + pW up front: global latency overlaps rt reads + MFMAs
    unsigned short kor[32];
    float pwr[8];
#pragma unroll
    for (int nt = 0; nt < 8; ++nt) {
        int col = nt * 16 + mrow;
        pwr[nt] = pW[col];
#pragma unroll
        for (int reg = 0; reg < 4; ++reg)
            kor[nt * 4 + reg] = Ko[(rbase + reg) * 128 + col];
    }

    s16x8 aF[4];
#pragma unroll
    for (int kb = 0; kb < 4; ++kb) {
        const float* s0 = r0p + (cw * 16 + mrow) * PSTR + kb * 32 + quad * 8;
        const float* s1 = r1p + (cw * 16 + mrow) * PSTR + kb * 32 + quad * 8;
        float4 xa = *(const float4*)s0, xb = *(const float4*)(s0 + 4);
        float4 ya = *(const float4*)s1, yb = *(const float4*)(s1 + 4);
        float4 sa, sb;
        sa.x = xa.x + ya.x; sa.y = xa.y + ya.y; sa.z = xa.z + ya.z; sa.w = xa.w + ya.w;
        sb.x = xb.x + yb.x; sb.y = xb.y + yb.y; sb.z = xb.z + yb.z; sb.w = xb.w + yb.w;
        aF[kb] = cvt8(sa, sb);
    }
    float p0 = 0.f, p1 = 0.f, p2 = 0.f, p3 = 0.f;
#pragma unroll
    for (int nt = 0; nt < 8; ++nt) {
        f32x4 acc = {0.f, 0.f, 0.f, 0.f};
#pragma unroll
        for (int kb = 0; kb < 4; ++kb) {
            s16x8 bf = *(const s16x8*)&fWl[(nt * 16 + mrow) * RSTR + kb * 32 + quad * 8];
            acc = __builtin_amdgcn_mfma_f32_16x16x32_bf16(aF[kb], bf, acc, 0, 0, 0);
        }
        float pw = pwr[nt];
        p0 = fmaf(fast_tanh(acc[0] + bf2f(kor[nt * 4 + 0])), pw, p0);
        p1 = fmaf(fast_tanh(acc[1] + bf2f(kor[nt * 4 + 1])), pw, p1);
        p2 = fmaf(fast_tanh(acc[2] + bf2f(kor[nt * 4 + 2])), pw, p2);
        p3 = fmaf(fast_tanh(acc[3] + bf2f(kor[nt * 4 + 3])), pw, p3);
    }
#pragma unroll
    for (int off = 1; off < 16; off <<= 1) {
        p0 += __shfl_xor(p0, off, 64); p1 += __shfl_xor(p1, off, 64);
        p2 += __shfl_xor(p2, off, 64); p3 += __shfl_xor(p3, off, 64);
    }
    if (mrow == 0) {
        int tb = t0 + gc * CH + cw * 16 + quad * 4;
        float ps[4] = {p0, p1, p2, p3};
#pragma unroll
        for (int reg = 0; reg < 4; ++reg) {
            int t = tb + reg;
            if (t < TT - 1) pred[b * (TT - 1) + t] = fast_sigmoid(ps[reg] + pbv);
        }
    }
}

__global__ __launch_bounds__(512, 1) void fused_kernel(
    const float* __restrict__ W, const unsigned* __restrict__ EA,
    const float* __restrict__ Mv0, const unsigned short* __restrict__ Ko,
    const unsigned short* __restrict__ fWat, const float* __restrict__ pW,
    const float* __restrict__ pb,
    float* __restrict__ pred, float* __restrict__ MvWS,
    int t0, int Tc, int doInit, int doSave)
{
    const int b = blockIdx.x;
    const int tid = threadIdx.x;
    const int nch = Tc / CH;
    const int role = tid >> 7;      // 0/1: producers, 2: consumers, 3: stagers
    const int dd = tid & 127;
    const int ch = role & 1;        // producer c-half (valid for role<2)
    const int ch16 = ch * 16;

    __shared__ __align__(16) float Wl[2][CH * WROW];            //  9.2 KB
    __shared__ __align__(16) float rt0[2][CH * PSTR];           // 33.8 KB
    __shared__ __align__(16) float rt1[2][CH * PSTR];           // 33.8 KB
    __shared__ __align__(16) unsigned EAl[2][CH * 128];         // 32.0 KB
    __shared__ __align__(16) unsigned short fWl[128 * RSTR];    // 34.8 KB

    // stage fWat -> fWl (all 512 threads)
    {
        int n = tid >> 2, k0 = (tid & 3) * 32;
#pragma unroll
        for (int j = 0; j < 4; ++j)
            *(s16x8*)&fWl[n * RSTR + k0 + j * 8] = *(const s16x8*)&fWat[n * 128 + k0 + j * 8];
    }

    const int lr = dd >> 2, lq = tid & 3;
    const float* __restrict__ Wb = W + (size_t)b * Tc * 32;
    const uint4* __restrict__ EA4 = (const uint4*)EA;
    const int bq = b * nch;
    f32x2 Mv2[8];
    float4 wr0, wr1;
    float4 w0, w1, w2_, w3_;
    float4 u0, u1, u2, u3;
    float pbv = 0.f;

    if (role < 2) {
        if (doInit) {
#pragma unroll
            for (int i = 0; i < 8; ++i)
                Mv2[i] = mk2(Mv0[(ch16 + 2 * i) * 128 + dd],
                             Mv0[(ch16 + 2 * i + 1) * 128 + dd]);
        } else {
#pragma unroll
            for (int i = 0; i < 8; ++i)
                Mv2[i] = mk2(MvWS[(size_t)b * 4096 + (ch16 + 2 * i) * 128 + dd],
                             MvWS[(size_t)b * 4096 + (ch16 + 2 * i + 1) * 128 + dd]);
        }
    } else if (role == 3) {
        LOAD_W(0); PUB_W(0);
        if (nch > 1) LOAD_W(1);
        STAGE_EA(0);
    } else {
        pbv = pb[0];
    }
    __syncthreads();

    for (int g = 0; g < nch; g += 2) {
        // ---- even chunk g: produce -> slot0; consume g-1 (slot1); stage ahead ----
        if (role < 2) {
            SEQ_CHUNK4(g);
        } else if (role == 2) {
            if (g >= 1)
                consume_chunk(g - 1, &rt0[(g - 1) & 1][0], &rt1[(g - 1) & 1][0],
                              fWl, b, Tc, t0, Ko, pW, pbv, pred, tid);
        } else {
            if (g + 1 < nch) { PUB_W(g + 1); STAGE_EA(g + 1); }
            if (g + 2 < nch) LOAD_W(g + 2);
        }
        __syncthreads();

        // ---- odd chunk g+1: produce -> slot1; consume g (slot0); stage ahead ----
        if (role < 2) {
            if (g + 1 < nch) SEQ_CHUNK4(g + 1);
        } else if (role == 2) {
            consume_chunk(g, &rt0[g & 1][0], &rt1[g & 1][0],
                          fWl, b, Tc, t0, Ko, pW, pbv, pred, tid);
        } else {
            if (g + 2 < nch) { PUB_W(g + 2); STAGE_EA(g + 2); }
            if (g + 3 < nch) LOAD_W(g + 3);
        }
        __syncthreads();
    }
    // epilogue: for even nch the last (odd) chunk is still unconsumed
    if (!(nch & 1) && role == 2) {
        consume_chunk(nch - 1, &rt0[(nch - 1) & 1][0], &rt1[(nch - 1) & 1][0],
                      fWl, b, Tc, t0, Ko, pW, pbv, pred, tid);
    }

    if (doSave && role < 2) {
#pragma unroll
        for (int i = 0; i < 8; ++i) {
            MvWS[(size_t)b * 4096 + (ch16 + 2 * i) * 128 + dd]     = Mv2[i].x;
            MvWS[(size_t)b * 4096 + (ch16 + 2 * i + 1) * 128 + dd] = Mv2[i].y;
        }
    }
}

// ---------------------------------------------------------------------------

extern "C" void kernel_launch(void* const* d_in, const int* in_sizes, int n_in,
                              void* d_out, int out_size, void* d_ws, size_t ws_size,
                              hipStream_t stream) {
    const int*   skills    = (const int*)d_in[0];
    const int*   responses = (const int*)d_in[1];
    const float* k_emb     = (const float*)d_in[2];
    const float* v_emb     = (const float*)d_in[3];
    const float* Mk        = (const float*)d_in[4];
    const float* Mv0       = (const float*)d_in[5];
    const float* f_W       = (const float*)d_in[6];
    const float* f_b       = (const float*)d_in[7];
    const float* p_W       = (const float*)d_in[8];
    const float* p_b       = (const float*)d_in[9];
    const float* e_W       = (const float*)d_in[10];
    const float* e_b       = (const float*)d_in[11];
    const float* a_W       = (const float*)d_in[12];
    const float* a_b       = (const float*)d_in[13];

    float* pred    = (float*)d_out;                 // [256][255]
    float* outTrue = pred + BB * (TT - 1);          // [256][255]

    // scratch per row: Wo 128 B + EA 512 B + Ko 256 B = 896 B
    int Tc = TT;
    for (;;) {
        size_t need = (size_t)BB * Tc * 896 + 69632 * 2;
        if (Tc < TT) need += (size_t)BB * 4096 * 4;
        if (need <= ws_size || Tc <= 32) break;
        Tc >>= 1;
    }

    char* p = (char*)d_ws;
    float* Wo = (float*)p;                     p += (size_t)BB * Tc * 32 * 4;
    unsigned* EA = (unsigned*)p;               p += (size_t)BB * Tc * 128 * 4;
    unsigned short* Ko = (unsigned short*)p;   p += (size_t)BB * Tc * 128 * 2;
    unsigned short* eWt = (unsigned short*)p;  p += 16384 * 2;
    unsigned short* aWt = (unsigned short*)p;  p += 16384 * 2;
    unsigned short* fWat = (unsigned short*)p; p += 16384 * 2;
    unsigned short* fWbt = (unsigned short*)p; p += 16384 * 2;
    unsigned short* Mkt = (unsigned short*)p;  p += 4096 * 2;
    float* MvWS = (float*)p;

    conv_kernel<<<272, 256, 0, stream>>>(e_W, a_W, f_W, Mk,
                                         eWt, aWt, fWat, fWbt, Mkt);

    for (int t0 = 0; t0 < TT; t0 += Tc) {
        pre_kernel<<<(BB * Tc) / 64, 256, 0, stream>>>(
            skills, responses, k_emb, v_emb, f_b, e_b, a_b,
            Mkt, fWbt, eWt, aWt, Wo, EA, Ko, outTrue, t0, Tc);
        fused_kernel<<<BB, 512, 0, stream>>>(
            Wo, EA, Mv0, Ko, fWat, p_W, p_b, pred, MvWS,
            t0, Tc, t0 == 0 ? 1 : 0, (t0 + Tc < TT) ? 1 : 0);
    }
}

// Round 16
// 155.039 us; speedup vs baseline: 1.0442x; 1.0442x over previous
//
#include <hip/hip_runtime.h>
#include <math.h>

// Problem constants (fixed by setup_inputs)
#define BB 256      // batch
#define TT 256      // time steps
#define NQ 1000     // num_q
#define DK 128
#define DV 128
#define CC 32

typedef short s16x8 __attribute__((ext_vector_type(8)));   // 8 bf16 bit-patterns
typedef float f32x4 __attribute__((ext_vector_type(4)));
typedef float f32x2 __attribute__((ext_vector_type(2)));

__device__ __forceinline__ float fast_sigmoid(float x) {
    x = fminf(fmaxf(x, -30.f), 30.f);
    return 1.f / (1.f + __expf(-x));
}
__device__ __forceinline__ float fast_tanh(float x) {
    x = fminf(fmaxf(x, -15.f), 15.f);
    float t = __expf(2.f * x);
    return (t - 1.f) / (t + 1.f);
}
__device__ __forceinline__ unsigned short f2bf(float f) {   // RNE fp32->bf16
    unsigned u = __float_as_uint(f);
    u += 0x7fffu + ((u >> 16) & 1u);
    return (unsigned short)(u >> 16);
}
__device__ __forceinline__ float bf2f(unsigned short h) {
    return __uint_as_float((unsigned)h << 16);
}
__device__ __forceinline__ f32x2 mk2(float x, float y) { f32x2 r; r.x = x; r.y = y; return r; }
__device__ __forceinline__ f32x2 fma2(f32x2 a, f32x2 b, f32x2 c) {
    return __builtin_elementwise_fma(a, b, c);
}
__device__ __forceinline__ s16x8 cvt8(float4 v0, float4 v1) {
    s16x8 f;
    f[0] = (short)f2bf(v0.x); f[1] = (short)f2bf(v0.y);
    f[2] = (short)f2bf(v0.z); f[3] = (short)f2bf(v0.w);
    f[4] = (short)f2bf(v1.x); f[5] = (short)f2bf(v1.y);
    f[6] = (short)f2bf(v1.z); f[7] = (short)f2bf(v1.w);
    return f;
}

// ---------------------------------------------------------------------------
// conv_kernel: build bf16 TRANSPOSED weights in ws (B-operand layout Wt[n][k])
// ---------------------------------------------------------------------------
__global__ __launch_bounds__(256) void conv_kernel(
    const float* __restrict__ eW, const float* __restrict__ aW,
    const float* __restrict__ fW, const float* __restrict__ Mk,
    unsigned short* __restrict__ eWt, unsigned short* __restrict__ aWt,
    unsigned short* __restrict__ fWat, unsigned short* __restrict__ fWbt,
    unsigned short* __restrict__ Mkt)
{
    int idx = blockIdx.x * 256 + threadIdx.x;
    if (idx < 16384) {
        int n = idx >> 7, k = idx & 127;
        eWt[idx] = f2bf(eW[k * 128 + n]);
    } else if (idx < 32768) {
        int i = idx - 16384; int n = i >> 7, k = i & 127;
        aWt[i] = f2bf(aW[k * 128 + n]);
    } else if (idx < 49152) {
        int i = idx - 32768; int n = i >> 7, k = i & 127;
        fWat[i] = f2bf(fW[k * 128 + n]);
    } else if (idx < 65536) {
        int i = idx - 49152; int n = i >> 7, k = i & 127;
        fWbt[i] = f2bf(fW[(128 + k) * 128 + n]);
    } else if (idx < 69632) {
        int i = idx - 65536; int n = i >> 7, k = i & 127;   // n=c 0..31
        Mkt[i] = f2bf(Mk[k * 32 + n]);
    }
}

// ---------------------------------------------------------------------------
// pre_kernel v2 (measured best form).
// ---------------------------------------------------------------------------
__global__ __launch_bounds__(256) void pre_kernel(
    const int* __restrict__ skills, const int* __restrict__ responses,
    const float* __restrict__ k_emb, const float* __restrict__ v_emb,
    const float* __restrict__ fb, const float* __restrict__ eb,
    const float* __restrict__ ab,
    const unsigned short* __restrict__ Mkt, const unsigned short* __restrict__ fWbt,
    const unsigned short* __restrict__ eWt, const unsigned short* __restrict__ aWt,
    float* __restrict__ Wo, unsigned* __restrict__ EA,
    unsigned short* __restrict__ Ko, float* __restrict__ outTrue,
    int t0, int Tc)
{
    const int tid = threadIdx.x;
    const int lane = tid & 63;
    const int m_base = (tid >> 6) * 16;
    const int mrow = lane & 15, quad = lane >> 4;
    const size_t base = (size_t)blockIdx.x * 64;

    __shared__ __align__(16) unsigned short Wlds[128 * 136];   // 34.8 KB

    // per-lane gather row (A-side): row = base + m_base + mrow
    int grow = (int)base + m_base + mrow;
    int gb = grow / Tc;
    int gt = t0 + (grow - gb * Tc);
    int gi = gb * TT + gt;
    int s = skills[gi];
    int r = responses[gi];
    int q = s + NQ * ((r > -1) ? r : 0);
    if (quad == 0 && gt >= 1) outTrue[gb * (TT - 1) + (gt - 1)] = (float)r;

    // stage Mkt rows 0..31
    {
        int n = tid >> 3, k0 = (tid & 7) * 16;
        *(s16x8*)&Wlds[n * 136 + k0]     = *(const s16x8*)&Mkt[n * 128 + k0];
        *(s16x8*)&Wlds[n * 136 + k0 + 8] = *(const s16x8*)&Mkt[n * 128 + k0 + 8];
    }

    // gather kt A-frags direct to regs: aF[kb] = kt[row][kb*32 + quad*8 ..+7]
    s16x8 aF[4];
    {
        const float* kr = k_emb + (size_t)s * DK + quad * 8;
#pragma unroll
        for (int kb = 0; kb < 4; ++kb)
            aF[kb] = cvt8(*(const float4*)(kr + kb * 32),
                          *(const float4*)(kr + kb * 32 + 4));
    }
    __syncthreads();   // [1] Mkt staged

    // logits (NT=2) + in-register softmax -> Wo
    {
        f32x4 l0 = {0.f, 0.f, 0.f, 0.f}, l1 = {0.f, 0.f, 0.f, 0.f};
#pragma unroll
        for (int kb = 0; kb < 4; ++kb) {
            s16x8 b0 = *(const s16x8*)&Wlds[mrow * 136 + kb * 32 + quad * 8];
            s16x8 b1 = *(const s16x8*)&Wlds[(16 + mrow) * 136 + kb * 32 + quad * 8];
            l0 = __builtin_amdgcn_mfma_f32_16x16x32_bf16(aF[kb], b0, l0, 0, 0, 0);
            l1 = __builtin_amdgcn_mfma_f32_16x16x32_bf16(aF[kb], b1, l1, 0, 0, 0);
        }
        // lane holds cols {mrow, 16+mrow} for rows m_base + quad*4 + reg
#pragma unroll
        for (int reg = 0; reg < 4; ++reg) {
            float a0 = l0[reg], a1 = l1[reg];
            float m = fmaxf(a0, a1);
#pragma unroll
            for (int off = 1; off < 16; off <<= 1)
                m = fmaxf(m, __shfl_xor(m, off, 64));
            float e0 = __expf(a0 - m), e1 = __expf(a1 - m);
            float ssum = e0 + e1;
#pragma unroll
            for (int off = 1; off < 16; off <<= 1)
                ssum += __shfl_xor(ssum, off, 64);
            float inv = 1.f / ssum;
            size_t rowg = base + m_base + quad * 4 + reg;
            Wo[rowg * 32 + mrow]      = e0 * inv;
            Wo[rowg * 32 + 16 + mrow] = e1 * inv;
        }
    }
    __syncthreads();   // [2] logits' Wlds reads done

    // stage fWbt
    {
        int n = tid >> 1, k0 = (tid & 1) * 64;
#pragma unroll
        for (int j = 0; j < 8; ++j)
            *(s16x8*)&Wlds[n * 136 + k0 + j * 8] = *(const s16x8*)&fWbt[n * 128 + k0 + j * 8];
    }
    __syncthreads();   // [3]

    // gather vt frags early (global latency overlaps ck MFMA below)
    s16x8 vF[4];
    {
        const float* vr = v_emb + (size_t)q * DV + quad * 8;
#pragma unroll
        for (int kb = 0; kb < 4; ++kb)
            vF[kb] = cvt8(*(const float4*)(vr + kb * 32),
                          *(const float4*)(vr + kb * 32 + 4));
    }

    // ck = kt@fWb + fb -> Ko
#pragma unroll
    for (int nt = 0; nt < 8; ++nt) {
        f32x4 acc = {0.f, 0.f, 0.f, 0.f};
#pragma unroll
        for (int kb = 0; kb < 4; ++kb) {
            s16x8 bf = *(const s16x8*)&Wlds[(nt * 16 + mrow) * 136 + kb * 32 + quad * 8];
            acc = __builtin_amdgcn_mfma_f32_16x16x32_bf16(aF[kb], bf, acc, 0, 0, 0);
        }
        int col = nt * 16 + mrow;
        float fbv = fb[col];
#pragma unroll
        for (int reg = 0; reg < 4; ++reg) {
            size_t rr = base + m_base + quad * 4 + reg;
            Ko[rr * 128 + col] = f2bf(acc[reg] + fbv);
        }
    }
    __syncthreads();   // [4] ck's Wlds reads done

    // stage eWt
    {
        int n = tid >> 1, k0 = (tid & 1) * 64;
#pragma unroll
        for (int j = 0; j < 8; ++j)
            *(s16x8*)&Wlds[n * 136 + k0 + j * 8] = *(const s16x8*)&eWt[n * 128 + k0 + j * 8];
    }
    __syncthreads();   // [5]

    // et = sigmoid(vt@eW + eb) -> registers
    float etr[8][4];
#pragma unroll
    for (int nt = 0; nt < 8; ++nt) {
        f32x4 acc = {0.f, 0.f, 0.f, 0.f};
#pragma unroll
        for (int kb = 0; kb < 4; ++kb) {
            s16x8 bf = *(const s16x8*)&Wlds[(nt * 16 + mrow) * 136 + kb * 32 + quad * 8];
            acc = __builtin_amdgcn_mfma_f32_16x16x32_bf16(vF[kb], bf, acc, 0, 0, 0);
        }
        int col = nt * 16 + mrow;
        float ebv = eb[col];
#pragma unroll
        for (int reg = 0; reg < 4; ++reg)
            etr[nt][reg] = fast_sigmoid(acc[reg] + ebv);
    }
    __syncthreads();   // [6] et's Wlds reads done

    // stage aWt
    {
        int n = tid >> 1, k0 = (tid & 1) * 64;
#pragma unroll
        for (int j = 0; j < 8; ++j)
            *(s16x8*)&Wlds[n * 136 + k0 + j * 8] = *(const s16x8*)&aWt[n * 128 + k0 + j * 8];
    }
    __syncthreads();   // [7]

    // at = tanh(vt@aW + ab); pack (et,at) -> EA
#pragma unroll
    for (int nt = 0; nt < 8; ++nt) {
        f32x4 acc = {0.f, 0.f, 0.f, 0.f};
#pragma unroll
        for (int kb = 0; kb < 4; ++kb) {
            s16x8 bf = *(const s16x8*)&Wlds[(nt * 16 + mrow) * 136 + kb * 32 + quad * 8];
            acc = __builtin_amdgcn_mfma_f32_16x16x32_bf16(vF[kb], bf, acc, 0, 0, 0);
        }
        int col = nt * 16 + mrow;
        float abv = ab[col];
#pragma unroll
        for (int reg = 0; reg < 4; ++reg) {
            size_t rr = base + m_base + quad * 4 + reg;
            int bb = (int)(rr / (size_t)Tc);
            int t  = (int)(rr - (size_t)bb * Tc);
            size_t o4 = (((size_t)bb * (Tc >> 5) + (t >> 5)) * 8 + ((t >> 2) & 7)) * 128 + col;
            unsigned lo = f2bf(etr[nt][reg]);
            unsigned hi = (unsigned)f2bf(fast_tanh(acc[reg] + abv)) << 16;
            EA[o4 * 4 + (t & 3)] = hi | lo;
        }
    }
}

// ---------------------------------------------------------------------------
// fused_kernel v14 (seq + post) — R26: EXACT restore of the best-measured
//  configuration (R10/R20: 155.76 µs total, fused 45.8).
//  Session ledger on the producer's ~860 cyc/step (8 probes, all reverted):
//   ILP depth 2 (+2%), lane-pair issue-halving+serial consume (−65%),
//   8-wave TLP (−15%), SMEM s_load staging (−76%), EA->LDS (+2% — kept),
//   setprio (−90%: starves co-phases), consume Ko prefetch (null),
//   rolled loop (−2%), SB-fence removal (−84%: fences are LOAD-BEARING —
//   without them the scheduler collapses the pipeline, confirming the
//   original design note). The SB-pinned dist-1 LDS pipeline + role-split
//   512-thread block is the measured optimum of every accessible axis:
//   a latency-bound 256-step serial recurrence at 1 critical wave per
//   half-column, balanced against consume/stage co-phases.
// ---------------------------------------------------------------------------

#define CH 32
#define WROW 36     // Wl row stride (floats)
#define RSTR 136    // fWl row stride (shorts)
#define PSTR 132    // rt partial row stride (floats)
#define SB() __builtin_amdgcn_sched_barrier(0)

#define LOAD_W(gg) do {                                                       \
    const float* ws = Wb + (size_t)(gg) * CH * 32;                            \
    wr0 = *(const float4*)(ws + dd * 8);                                      \
    wr1 = *(const float4*)(ws + dd * 8 + 4);                                  \
} while (0)

#define PUB_W(gg) do {                                                        \
    float* wd = &Wl[(gg) & 1][lr * WROW + lq * 8];                            \
    *(float4*)wd = wr0; *(float4*)(wd + 4) = wr1;                             \
} while (0)

// stager: copy chunk gg's EA block global->LDS, transposed to [tl][dd]
#define STAGE_EA(gg) do {                                                     \
    const uint4* src = EA4 + ((size_t)(bq + (gg))) * 1024 + dd;               \
    unsigned* dst = &EAl[(gg) & 1][0];                                        \
    _Pragma("unroll")                                                         \
    for (int j = 0; j < 8; ++j) {                                             \
        uint4 v = src[j * 128];                                               \
        dst[(4 * j + 0) * 128 + dd] = v.x;                                    \
        dst[(4 * j + 1) * 128 + dd] = v.y;                                    \
        dst[(4 * j + 2) * 128 + dd] = v.z;                                    \
        dst[(4 * j + 3) * 128 + dd] = v.w;                                    \
    }                                                                         \
} while (0)

// prefetch this producer's 16 w floats of row `rowidx` into 4 named float4s
#define PREF4(A0,A1,A2,A3, rowidx) do {                                       \
    const float* _wr = wlc + (rowidx) * WROW;                                 \
    A0 = *(const float4*)(_wr + 0);  A1 = *(const float4*)(_wr + 4);          \
    A2 = *(const float4*)(_wr + 8);  A3 = *(const float4*)(_wr + 12);         \
} while (0)

// one chain step on this producer's 16-c half; f32 partial -> own LDS array
#define STEP4(A0,A1,A2,A3, EAV, tl) do {                                      \
    f32x2 w2[8];                                                              \
    w2[0] = mk2(A0.x, A0.y); w2[1] = mk2(A0.z, A0.w);                         \
    w2[2] = mk2(A1.x, A1.y); w2[3] = mk2(A1.z, A1.w);                         \
    w2[4] = mk2(A2.x, A2.y); w2[5] = mk2(A2.z, A2.w);                         \
    w2[6] = mk2(A3.x, A3.y); w2[7] = mk2(A3.z, A3.w);                         \
    unsigned ea = (EAV);                                                      \
    float e  = __uint_as_float(ea << 16);                                     \
    float av = __uint_as_float(ea & 0xffff0000u);                             \
    f32x2 ne2 = mk2(-e, -e);                                                  \
    f32x2 a2  = mk2(av, av);                                                  \
    f32x2 r0 = mk2(0.f, 0.f), r1 = r0, r2 = r0, r3 = r0;                      \
    r0 = fma2(w2[0], Mv2[0], r0); r1 = fma2(w2[1], Mv2[1], r1);               \
    r2 = fma2(w2[2], Mv2[2], r2); r3 = fma2(w2[3], Mv2[3], r3);               \
    r0 = fma2(w2[4], Mv2[4], r0); r1 = fma2(w2[5], Mv2[5], r1);               \
    r2 = fma2(w2[6], Mv2[6], r2); r3 = fma2(w2[7], Mv2[7], r3);               \
    f32x2 rs = (r0 + r1) + (r2 + r3);                                         \
    slp[(tl) * PSTR + dd] = rs.x + rs.y;                                      \
    _Pragma("unroll")                                                         \
    for (int i = 0; i < 8; ++i)                                               \
        Mv2[i] = fma2(w2[i], fma2(ne2, Mv2[i], a2), Mv2[i]);                  \
} while (0)

// chunk: distance-1 SB-pinned pipeline for w (LDS) and ea (LDS)
#define SEQ_CHUNK4(gg) do {                                                   \
    const float* wlc = Wl[(gg) & 1] + ch16;                                   \
    const unsigned* eac = &EAl[(gg) & 1][0];                                  \
    float* slp = ch ? &rt1[(gg) & 1][0] : &rt0[(gg) & 1][0];                  \
    PREF4(w0, w1, w2_, w3_, 0);                                               \
    unsigned eaw = eac[dd], eau;                                              \
    _Pragma("unroll")                                                         \
    for (int tp = 0; tp < 16; ++tp) {                                         \
        SB(); PREF4(u0, u1, u2, u3, 2 * tp + 1);                              \
        eau = eac[(2 * tp + 1) * 128 + dd]; SB();                             \
        STEP4(w0, w1, w2_, w3_, eaw, 2 * tp);                                 \
        SB(); PREF4(w0, w1, w2_, w3_,                                         \
                    (2 * tp + 2 < 32) ? (2 * tp + 2) : 31);                   \
        eaw = eac[((2 * tp + 2 < 32) ? (2 * tp + 2) : 31) * 128 + dd]; SB();  \
        STEP4(u0, u1, u2, u3, eau, 2 * tp + 1);                               \
    }                                                                         \
} while (0)

__device__ __forceinline__ void consume_chunk(
    int gc, const float* r0p, const float* r1p, const unsigned short* fWl,
    int b, int Tc, int t0,
    const unsigned short* __restrict__ Ko, const float* __restrict__ pW,
    float pbv, float* __restrict__ pred, int tid)
{
    const int lane = tid & 63;
    const int cw = (tid >> 6) & 1;          // consumer wave 0/1 -> rows cw*16..+15
    const int mrow = lane & 15, quad = lane >> 4;
    s16x8 aF[4];
#pragma unroll
    for (int kb = 0; kb < 4; ++kb) {
        const float* s0 = r0p + (cw * 16 + mrow) * PSTR + kb * 32 + quad * 8;
        const float* s1 = r1p + (cw * 16 + mrow) * PSTR + kb * 32 + quad * 8;
        float4 xa = *(const float4*)s0, xb = *(const float4*)(s0 + 4);
        float4 ya = *(const float4*)s1, yb = *(const float4*)(s1 + 4);
        float4 sa, sb;
        sa.x = xa.x + ya.x; sa.y = xa.y + ya.y; sa.z = xa.z + ya.z; sa.w = xa.w + ya.w;
        sb.x = xb.x + yb.x; sb.y = xb.y + yb.y; sb.z = xb.z + yb.z; sb.w = xb.w + yb.w;
        aF[kb] = cvt8(sa, sb);
    }
    float p0 = 0.f, p1 = 0.f, p2 = 0.f, p3 = 0.f;
    size_t rbase = (size_t)b * Tc + gc * CH + cw * 16 + quad * 4;
#pragma unroll
    for (int nt = 0; nt < 8; ++nt) {
        f32x4 acc = {0.f, 0.f, 0.f, 0.f};
#pragma unroll
        for (int kb = 0; kb < 4; ++kb) {
            s16x8 bf = *(const s16x8*)&fWl[(nt * 16 + mrow) * RSTR + kb * 32 + quad * 8];
            acc = __builtin_amdgcn_mfma_f32_16x16x32_bf16(aF[kb], bf, acc, 0, 0, 0);
        }
        int col = nt * 16 + mrow;
        float pw = pW[col];
        p0 = fmaf(fast_tanh(acc[0] + bf2f(Ko[(rbase + 0) * 128 + col])), pw, p0);
        p1 = fmaf(fast_tanh(acc[1] + bf2f(Ko[(rbase + 1) * 128 + col])), pw, p1);
        p2 = fmaf(fast_tanh(acc[2] + bf2f(Ko[(rbase + 2) * 128 + col])), pw, p2);
        p3 = fmaf(fast_tanh(acc[3] + bf2f(Ko[(rbase + 3) * 128 + col])), pw, p3);
    }
#pragma unroll
    for (int off = 1; off < 16; off <<= 1) {
        p0 += __shfl_xor(p0, off, 64); p1 += __shfl_xor(p1, off, 64);
        p2 += __shfl_xor(p2, off, 64); p3 += __shfl_xor(p3, off, 64);
    }
    if (mrow == 0) {
        int tb = t0 + gc * CH + cw * 16 + quad * 4;
        float ps[4] = {p0, p1, p2, p3};
#pragma unroll
        for (int reg = 0; reg < 4; ++reg) {
            int t = tb + reg;
            if (t < TT - 1) pred[b * (TT - 1) + t] = fast_sigmoid(ps[reg] + pbv);
        }
    }
}

__global__ __launch_bounds__(512, 1) void fused_kernel(
    const float* __restrict__ W, const unsigned* __restrict__ EA,
    const float* __restrict__ Mv0, const unsigned short* __restrict__ Ko,
    const unsigned short* __restrict__ fWat, const float* __restrict__ pW,
    const float* __restrict__ pb,
    float* __restrict__ pred, float* __restrict__ MvWS,
    int t0, int Tc, int doInit, int doSave)
{
    const int b = blockIdx.x;
    const int tid = threadIdx.x;
    const int nch = Tc / CH;
    const int role = tid >> 7;      // 0/1: producers, 2: consumers, 3: stagers
    const int dd = tid & 127;
    const int ch = role & 1;        // producer c-half (valid for role<2)
    const int ch16 = ch * 16;

    __shared__ __align__(16) float Wl[2][CH * WROW];            //  9.2 KB
    __shared__ __align__(16) float rt0[2][CH * PSTR];           // 33.8 KB
    __shared__ __align__(16) float rt1[2][CH * PSTR];           // 33.8 KB
    __shared__ __align__(16) unsigned EAl[2][CH * 128];         // 32.0 KB
    __shared__ __align__(16) unsigned short fWl[128 * RSTR];    // 34.8 KB

    // stage fWat -> fWl (all 512 threads)
    {
        int n = tid >> 2, k0 = (tid & 3) * 32;
#pragma unroll
        for (int j = 0; j < 4; ++j)
            *(s16x8*)&fWl[n * RSTR + k0 + j * 8] = *(const s16x8*)&fWat[n * 128 + k0 + j * 8];
    }

    const int lr = dd >> 2, lq = tid & 3;
    const float* __restrict__ Wb = W + (size_t)b * Tc * 32;
    const uint4* __restrict__ EA4 = (const uint4*)EA;
    const int bq = b * nch;
    f32x2 Mv2[8];
    float4 wr0, wr1;
    float4 w0, w1, w2_, w3_;
    float4 u0, u1, u2, u3;
    float pbv = 0.f;

    if (role < 2) {
        if (doInit) {
#pragma unroll
            for (int i = 0; i < 8; ++i)
                Mv2[i] = mk2(Mv0[(ch16 + 2 * i) * 128 + dd],
                             Mv0[(ch16 + 2 * i + 1) * 128 + dd]);
        } else {
#pragma unroll
            for (int i = 0; i < 8; ++i)
                Mv2[i] = mk2(MvWS[(size_t)b * 4096 + (ch16 + 2 * i) * 128 + dd],
                             MvWS[(size_t)b * 4096 + (ch16 + 2 * i + 1) * 128 + dd]);
        }
    } else if (role == 3) {
        LOAD_W(0); PUB_W(0);
        if (nch > 1) LOAD_W(1);
        STAGE_EA(0);
    } else {
        pbv = pb[0];
    }
    __syncthreads();

    for (int g = 0; g < nch; g += 2) {
        // ---- even chunk g: produce -> slot0; consume g-1 (slot1); stage ahead ----
        if (role < 2) {
            SEQ_CHUNK4(g);
        } else if (role == 2) {
            if (g >= 1)
                consume_chunk(g - 1, &rt0[(g - 1) & 1][0], &rt1[(g - 1) & 1][0],
                              fWl, b, Tc, t0, Ko, pW, pbv, pred, tid);
        } else {
            if (g + 1 < nch) { PUB_W(g + 1); STAGE_EA(g + 1); }
            if (g + 2 < nch) LOAD_W(g + 2);
        }
        __syncthreads();

        // ---- odd chunk g+1: produce -> slot1; consume g (slot0); stage ahead ----
        if (role < 2) {
            if (g + 1 < nch) SEQ_CHUNK4(g + 1);
        } else if (role == 2) {
            consume_chunk(g, &rt0[g & 1][0], &rt1[g & 1][0],
                          fWl, b, Tc, t0, Ko, pW, pbv, pred, tid);
        } else {
            if (g + 2 < nch) { PUB_W(g + 2); STAGE_EA(g + 2); }
            if (g + 3 < nch) LOAD_W(g + 3);
        }
        __syncthreads();
    }
    // epilogue: for even nch the last (odd) chunk is still unconsumed
    if (!(nch & 1) && role == 2) {
        consume_chunk(nch - 1, &rt0[(nch - 1) & 1][0], &rt1[(nch - 1) & 1][0],
                      fWl, b, Tc, t0, Ko, pW, pbv, pred, tid);
    }

    if (doSave && role < 2) {
#pragma unroll
        for (int i = 0; i < 8; ++i) {
            MvWS[(size_t)b * 4096 + (ch16 + 2 * i) * 128 + dd]     = Mv2[i].x;
            MvWS[(size_t)b * 4096 + (ch16 + 2 * i + 1) * 128 + dd] = Mv2[i].y;
        }
    }
}

// ---------------------------------------------------------------------------

extern "C" void kernel_launch(void* const* d_in, const int* in_sizes, int n_in,
                              void* d_out, int out_size, void* d_ws, size_t ws_size,
                              hipStream_t stream) {
    const int*   skills    = (const int*)d_in[0];
    const int*   responses = (const int*)d_in[1];
    const float* k_emb     = (const float*)d_in[2];
    const float* v_emb     = (const float*)d_in[3];
    const float* Mk        = (const float*)d_in[4];
    const float* Mv0       = (const float*)d_in[5];
    const float* f_W       = (const float*)d_in[6];
    const float* f_b       = (const float*)d_in[7];
    const float* p_W       = (const float*)d_in[8];
    const float* p_b       = (const float*)d_in[9];
    const float* e_W       = (const float*)d_in[10];
    const float* e_b       = (const float*)d_in[11];
    const float* a_W       = (const float*)d_in[12];
    const float* a_b       = (const float*)d_in[13];

    float* pred    = (float*)d_out;                 // [256][255]
    float* outTrue = pred + BB * (TT - 1);          // [256][255]

    // scratch per row: Wo 128 B + EA 512 B + Ko 256 B = 896 B
    int Tc = TT;
    for (;;) {
        size_t need = (size_t)BB * Tc * 896 + 69632 * 2;
        if (Tc < TT) need += (size_t)BB * 4096 * 4;
        if (need <= ws_size || Tc <= 32) break;
        Tc >>= 1;
    }

    char* p = (char*)d_ws;
    float* Wo = (float*)p;                     p += (size_t)BB * Tc * 32 * 4;
    unsigned* EA = (unsigned*)p;               p += (size_t)BB * Tc * 128 * 4;
    unsigned short* Ko = (unsigned short*)p;   p += (size_t)BB * Tc * 128 * 2;
    unsigned short* eWt = (unsigned short*)p;  p += 16384 * 2;
    unsigned short* aWt = (unsigned short*)p;  p += 16384 * 2;
    unsigned short* fWat = (unsigned short*)p; p += 16384 * 2;
    unsigned short* fWbt = (unsigned short*)p; p += 16384 * 2;
    unsigned short* Mkt = (unsigned short*)p;  p += 4096 * 2;
    float* MvWS = (float*)p;

    conv_kernel<<<272, 256, 0, stream>>>(e_W, a_W, f_W, Mk,
                                         eWt, aWt, fWat, fWbt, Mkt);

    for (int t0 = 0; t0 < TT; t0 += Tc) {
        pre_kernel<<<(BB * Tc) / 64, 256, 0, stream>>>(
            skills, responses, k_emb, v_emb, f_b, e_b, a_b,
            Mkt, fWbt, eWt, aWt, Wo, EA, Ko, outTrue, t0, Tc);
        fused_kernel<<<BB, 512, 0, stream>>>(
            Wo, EA, Mv0, Ko, fWat, p_W, p_b, pred, MvWS,
            t0, Tc, t0 == 0 ? 1 : 0, (t0 + Tc < TT) ? 1 : 0);
    }
}